// Round 6
// baseline (9358.726 us; speedup 1.0000x reference)
//
#include <hip/hip_runtime.h>
#include <hip/hip_bf16.h>
#include <math.h>
#include <stdint.h>

using bf16 = __hip_bfloat16;
typedef __attribute__((ext_vector_type(8))) short short8;   // 8 bf16 (MFMA A/B frag)
typedef __attribute__((ext_vector_type(4))) float floatx4;  // MFMA C/D frag (f32)
typedef __attribute__((ext_vector_type(4))) int int4v;      // i8 K=64 frag / i32 acc

// tanh(x) = 1 - 2/(exp(2x)+1)
__device__ __forceinline__ float fast_tanh(float x) {
    float e = __expf(2.f * x);
    return 1.f - 2.f / (e + 1.f);
}

// ===========================================================================
// Row-resident, ACTIVATIONS-IN-LDS persistent kernel (R5 post-mortem: 17.9GB
// HBM fetch = weights evicted from L2 every eval by the streaming activation
// round-trips; 4MB/XCD L2 can't hold 3MB weights + 4MB/XCD activation slice).
//
// Fix: x0 (32KB bf16) + x1 (32KB i8) + x2 (64KB bf16) live in 128KB LDS per
// block; activations NEVER touch global. L2 then holds only the 3MB weights
// (< 4MB/XCD), permanently hot: steady-state HBM traffic ~ zero. Weight
// B-frags load direct global->VGPR (L2-hit ~200cy) with a register double
// buffer (prefetch next half-K while MFMA'ing current) to hide latency.
//
// A-frags read from LDS with the same XOR-8 16B-chunk swizzle and identical
// MFMA K-order as the verified R1/R5 cores => numerics identical to R5
// (passed, absmax 0.0625). LDS layouts (both write & read sides swizzled):
//   x0 (m,e): m*1024 + ((e>>3 ^ m&7)<<4) + (e&7)*2     e=0..511 bf16
//   x1 (m,n): m*1024 + ((n>>4 ^ m&7)<<4) + (n&15)      n=0..1023 i8
//   x2 (m,e): m*2048 + ((e>>3 ^ m&7)<<4) + (e&7)*2     e=0..1023 bf16
// Frag reads hit 8 distinct 16B slots per 16 lanes -> 2-way = free.
//
// Block: 512 thr (8 waves), 1 block/CU (128KB LDS), grid 256 = 1/CU.
// hreg/kacc (RK4 state) in VGPRs for the whole kernel. Zero grid barriers.
// ===========================================================================

// L1: x1 = i8(tanh(x0 . W1^T + b1) * 127).  M=32, N=1024, K=512.
__device__ __forceinline__ void phase1(const bf16* __restrict__ W,
                                       const float* __restrict__ bias,
                                       const char* __restrict__ x0l,
                                       char* __restrict__ x1l) {
    const int tid = threadIdx.x;
    const int lane = tid & 63, w = tid >> 6;
    const int quad = lane >> 4, l16 = lane & 15;
    const int x7 = l16 & 7;

    floatx4 acc[2][8];
    const floatx4 zero = {0.f, 0.f, 0.f, 0.f};
#pragma unroll
    for (int mt = 0; mt < 2; ++mt)
#pragma unroll
        for (int nt = 0; nt < 8; ++nt) acc[mt][nt] = zero;

    const bf16* wp = W + (size_t)(w * 128 + l16) * 512 + quad * 8;
    short8 bA[8], bB[8];
#pragma unroll
    for (int nt = 0; nt < 8; ++nt) bA[nt] = *(const short8*)(wp + nt * 8192);

    for (int kt = 0; kt < 8; ++kt) {
#pragma unroll
        for (int nt = 0; nt < 8; ++nt)
            bB[nt] = *(const short8*)(wp + nt * 8192 + kt * 64 + 32);
        {
            const int c = kt * 8 + quad;          // kk = 0
            short8 af[2];
#pragma unroll
            for (int mt = 0; mt < 2; ++mt)
                af[mt] = *(const short8*)(x0l + (mt * 16 + l16) * 1024 + ((c ^ x7) << 4));
#pragma unroll
            for (int mt = 0; mt < 2; ++mt)
#pragma unroll
                for (int nt = 0; nt < 8; ++nt)
                    acc[mt][nt] = __builtin_amdgcn_mfma_f32_16x16x32_bf16(
                        af[mt], bA[nt], acc[mt][nt], 0, 0, 0);
        }
        if (kt + 1 < 8) {
#pragma unroll
            for (int nt = 0; nt < 8; ++nt)
                bA[nt] = *(const short8*)(wp + nt * 8192 + (kt + 1) * 64);
        }
        {
            const int c = kt * 8 + 4 + quad;      // kk = 1
            short8 af[2];
#pragma unroll
            for (int mt = 0; mt < 2; ++mt)
                af[mt] = *(const short8*)(x0l + (mt * 16 + l16) * 1024 + ((c ^ x7) << 4));
#pragma unroll
            for (int mt = 0; mt < 2; ++mt)
#pragma unroll
                for (int nt = 0; nt < 8; ++nt)
                    acc[mt][nt] = __builtin_amdgcn_mfma_f32_16x16x32_bf16(
                        af[mt], bB[nt], acc[mt][nt], 0, 0, 0);
        }
    }

    const int n0 = w * 128 + l16;
#pragma unroll
    for (int mt = 0; mt < 2; ++mt)
#pragma unroll
        for (int nt = 0; nt < 8; ++nt) {
            const int n = n0 + nt * 16;
            const float bb = bias[n];
#pragma unroll
            for (int i = 0; i < 4; ++i) {
                const int m = mt * 16 + quad * 4 + i;
                const float t = fast_tanh(acc[mt][nt][i] + bb);
                *(int8_t*)(x1l + m * 1024 + ((((n >> 4) ^ (m & 7)) << 4) | (n & 15))) =
                    (int8_t)__float2int_rn(t * 127.f);
            }
        }
}

// L2: x2 = bf16(tanh(acc*dq[n] + b2)), i8 core. M=32, N=1024, K=1024.
__device__ __forceinline__ void phase2(const int8_t* __restrict__ W,
                                       const float* __restrict__ dq,
                                       const float* __restrict__ bias,
                                       const char* __restrict__ x1l,
                                       char* __restrict__ x2l) {
    const int tid = threadIdx.x;
    const int lane = tid & 63, w = tid >> 6;
    const int quad = lane >> 4, l16 = lane & 15;
    const int x7 = l16 & 7;

    int4v acc[2][8];
    const int4v izero = {0, 0, 0, 0};
#pragma unroll
    for (int mt = 0; mt < 2; ++mt)
#pragma unroll
        for (int nt = 0; nt < 8; ++nt) acc[mt][nt] = izero;

    const int8_t* wp = W + (size_t)(w * 128 + l16) * 1024 + quad * 16;
    int4v bA[8], bB[8];
#pragma unroll
    for (int nt = 0; nt < 8; ++nt) bA[nt] = *(const int4v*)(wp + nt * 16384);

    for (int kt = 0; kt < 8; ++kt) {
#pragma unroll
        for (int nt = 0; nt < 8; ++nt)
            bB[nt] = *(const int4v*)(wp + nt * 16384 + kt * 128 + 64);
        {
            const int c = kt * 8 + quad;          // kk = 0
            int4v af[2];
#pragma unroll
            for (int mt = 0; mt < 2; ++mt)
                af[mt] = *(const int4v*)(x1l + (mt * 16 + l16) * 1024 + ((c ^ x7) << 4));
#pragma unroll
            for (int mt = 0; mt < 2; ++mt)
#pragma unroll
                for (int nt = 0; nt < 8; ++nt)
                    acc[mt][nt] = __builtin_amdgcn_mfma_i32_16x16x64_i8(
                        af[mt], bA[nt], acc[mt][nt], 0, 0, 0);
        }
        if (kt + 1 < 8) {
#pragma unroll
            for (int nt = 0; nt < 8; ++nt)
                bA[nt] = *(const int4v*)(wp + nt * 16384 + (kt + 1) * 128);
        }
        {
            const int c = kt * 8 + 4 + quad;      // kk = 1
            int4v af[2];
#pragma unroll
            for (int mt = 0; mt < 2; ++mt)
                af[mt] = *(const int4v*)(x1l + (mt * 16 + l16) * 1024 + ((c ^ x7) << 4));
#pragma unroll
            for (int mt = 0; mt < 2; ++mt)
#pragma unroll
                for (int nt = 0; nt < 8; ++nt)
                    acc[mt][nt] = __builtin_amdgcn_mfma_i32_16x16x64_i8(
                        af[mt], bB[nt], acc[mt][nt], 0, 0, 0);
        }
    }

    const int n0 = w * 128 + l16;
#pragma unroll
    for (int mt = 0; mt < 2; ++mt)
#pragma unroll
        for (int nt = 0; nt < 8; ++nt) {
            const int n = n0 + nt * 16;
            const float bb = bias[n];
            const float dqn = dq[n];
#pragma unroll
            for (int i = 0; i < 4; ++i) {
                const int m = mt * 16 + quad * 4 + i;
                *(bf16*)(x2l + m * 2048 + ((((n >> 3) ^ (m & 7)) << 4) | ((n & 7) * 2))) =
                    __float2bfloat16(fast_tanh((float)acc[mt][nt][i] * dqn + bb));
            }
        }
}

__global__ void __launch_bounds__(512, 2)
ode_lds(const float* __restrict__ h_in, float* __restrict__ h_fin,
        const bf16* __restrict__ W1b, const float* __restrict__ b1,
        const int8_t* __restrict__ W2i, const float* __restrict__ dqv,
        const float* __restrict__ b2,
        const bf16* __restrict__ W3b, const float* __restrict__ b3,
        const float* __restrict__ temb) {
    __shared__ alignas(16) char smem[131072];
    char* x0l = smem;             // 32 KB bf16 [32][512]
    char* x1l = smem + 32768;     // 32 KB i8  [32][1024]
    char* x2l = smem + 65536;     // 64 KB bf16[32][1024]

    const int row0 = blockIdx.x * 32;          // 256 blocks x 32 rows
    const int tid = threadIdx.x;
    const int lane = tid & 63, w = tid >> 6;
    const int quad = lane >> 4, l16 = lane & 15;
    const int x7 = l16 & 7;
    const float dt = 0.1f;

    // ---- init: x0_lds = bf16(h + temb[0]); hreg = h; kacc = 0 ----
    for (int idx = tid; idx < 32 * 512; idx += 512) {
        const int m = idx >> 9, e = idx & 511;
        const float v = h_in[(size_t)(row0 + m) * 512 + e] + temb[e];
        *(bf16*)(x0l + m * 1024 + ((((e >> 3) ^ (m & 7)) << 4) | ((e & 7) * 2))) =
            __float2bfloat16(v);
    }
    // per-thread RK4 state; element j=(mt*4+nt)*4+i maps to
    // m = row0 + mt*16 + quad*4 + i, n = w*64 + nt*16 + l16 (L3 tile map)
    float hreg[32], kacc[32];
#pragma unroll
    for (int mt = 0; mt < 2; ++mt)
#pragma unroll
        for (int nt = 0; nt < 4; ++nt)
#pragma unroll
            for (int i = 0; i < 4; ++i)
                hreg[(mt * 4 + nt) * 4 + i] =
                    h_in[(size_t)(row0 + mt * 16 + quad * 4 + i) * 512 +
                         (w * 64 + nt * 16 + l16)];
#pragma unroll
    for (int j = 0; j < 32; ++j) kacc[j] = 0.f;

    for (int s = 0; s < 10; ++s) {
        const float* tmid = temb + (size_t)(2 * s + 1) * 512;
        const float* tend = temb + (size_t)(2 * s + 2) * 512;
        for (int e = 0; e < 4; ++e) {
            __syncthreads();                    // x0 writes visible
            phase1(W1b, b1, x0l, x1l);
            __syncthreads();                    // x1 writes visible
            phase2(W2i, dqv, b2, x1l, x2l);
            __syncthreads();                    // x2 writes visible

            // ---- L3: M=32, N=512, K=1024, A = x2_lds, reg-dbuf W ----
            floatx4 acc3[2][4];
            const floatx4 zero = {0.f, 0.f, 0.f, 0.f};
#pragma unroll
            for (int mt = 0; mt < 2; ++mt)
#pragma unroll
                for (int nt = 0; nt < 4; ++nt) acc3[mt][nt] = zero;

            const bf16* wp3 = W3b + (size_t)(w * 64 + l16) * 1024 + quad * 8;
            short8 cA[4], cB[4];
#pragma unroll
            for (int nt = 0; nt < 4; ++nt) cA[nt] = *(const short8*)(wp3 + nt * 16384);

            for (int kt = 0; kt < 16; ++kt) {
#pragma unroll
                for (int nt = 0; nt < 4; ++nt)
                    cB[nt] = *(const short8*)(wp3 + nt * 16384 + kt * 64 + 32);
                {
                    const int c = kt * 8 + quad;          // kk = 0
                    short8 af[2];
#pragma unroll
                    for (int mt = 0; mt < 2; ++mt)
                        af[mt] = *(const short8*)(x2l + (mt * 16 + l16) * 2048 +
                                                  ((c ^ x7) << 4));
#pragma unroll
                    for (int mt = 0; mt < 2; ++mt)
#pragma unroll
                        for (int nt = 0; nt < 4; ++nt)
                            acc3[mt][nt] = __builtin_amdgcn_mfma_f32_16x16x32_bf16(
                                af[mt], cA[nt], acc3[mt][nt], 0, 0, 0);
                }
                if (kt + 1 < 16) {
#pragma unroll
                    for (int nt = 0; nt < 4; ++nt)
                        cA[nt] = *(const short8*)(wp3 + nt * 16384 + (kt + 1) * 64);
                }
                {
                    const int c = kt * 8 + 4 + quad;      // kk = 1
                    short8 af[2];
#pragma unroll
                    for (int mt = 0; mt < 2; ++mt)
                        af[mt] = *(const short8*)(x2l + (mt * 16 + l16) * 2048 +
                                                  ((c ^ x7) << 4));
#pragma unroll
                    for (int mt = 0; mt < 2; ++mt)
#pragma unroll
                        for (int nt = 0; nt < 4; ++nt)
                            acc3[mt][nt] = __builtin_amdgcn_mfma_f32_16x16x32_bf16(
                                af[mt], cB[nt], acc3[mt][nt], 0, 0, 0);
                }
            }
            __syncthreads();                    // x2 reads done before x0 overwrite

            // ---- RK4 epilogue (register kacc/h, x0 written to LDS) ----
            const float* te = (e <= 1) ? tmid : tend;
#pragma unroll
            for (int mt = 0; mt < 2; ++mt)
#pragma unroll
                for (int nt = 0; nt < 4; ++nt) {
                    const int n = w * 64 + nt * 16 + l16;
                    const float bb = b3[n];
                    const float tv = te[n];
#pragma unroll
                    for (int i = 0; i < 4; ++i) {
                        const int j = (mt * 4 + nt) * 4 + i;
                        const int m = mt * 16 + quad * 4 + i;
                        const float kv = acc3[mt][nt][i] + bb;
                        float xnew;
                        if (e == 0) {
                            kacc[j] = kv;
                            const float hbf = __bfloat162float(__float2bfloat16(hreg[j]));
                            xnew = hbf + 0.05f * kv + tv;
                        } else if (e == 1) {
                            kacc[j] += 2.f * kv;
                            const float hbf = __bfloat162float(__float2bfloat16(hreg[j]));
                            xnew = hbf + 0.05f * kv + tv;
                        } else if (e == 2) {
                            kacc[j] += 2.f * kv;
                            const float hbf = __bfloat162float(__float2bfloat16(hreg[j]));
                            xnew = hbf + 0.1f * kv + tv;
                        } else {
                            const float hn = hreg[j] + (dt / 6.f) * (kacc[j] + kv);
                            hreg[j] = hn;
                            if (s == 9) {
                                h_fin[(size_t)(row0 + m) * 512 + n] = hn;
                                continue;
                            }
                            xnew = hn + tv;
                        }
                        *(bf16*)(x0l + m * 1024 +
                                 ((((n >> 3) ^ (m & 7)) << 4) | ((n & 7) * 2))) =
                            __float2bfloat16(xnew);
                    }
                }
        }
    }
}

// ===========================================================================
// Prep kernels.
// ===========================================================================

__global__ void f2b_kern(const float* __restrict__ src, bf16* __restrict__ dst, int n) {
    const int i = blockIdx.x * blockDim.x + threadIdx.x;
    if (i < n) dst[i] = __float2bfloat16(src[i]);
}

// Per-row i8 quantization of W2 (N=1024 rows, K=1024): row n scaled by
// 127/rowmax_n (clamped), dq[n] = rowmax_n/127^2 (includes x1's /127).
__global__ void quantW2_row(const float* __restrict__ W, int K,
                            int8_t* __restrict__ out, float* __restrict__ dq) {
    __shared__ float red[256];
    const int row = blockIdx.x, tid = threadIdx.x;
    const float* src = W + (size_t)row * K;
    float m = 0.f;
    for (int k = tid; k < K; k += 256) m = fmaxf(m, fabsf(src[k]));
    red[tid] = m;
    __syncthreads();
    for (int s = 128; s > 0; s >>= 1) {
        if (tid < s) red[tid] = fmaxf(red[tid], red[tid + s]);
        __syncthreads();
    }
    const float rmax = fmaxf(red[0], 1e-8f);
    const float sc = 127.f / rmax;
    int8_t* dst = out + (size_t)row * K;
    for (int k = tid; k < K; k += 256) {
        int v = __float2int_rn(src[k] * sc);
        v = v > 127 ? 127 : (v < -127 ? -127 : v);
        dst[k] = (int8_t)v;
    }
    if (tid == 0) dq[row] = rmax / (127.f * 127.f);
}

// temb[j][n] = (j*dt/2)*Wt[n] + bt[n], j = 0..20
__global__ void temb_kern(const float* __restrict__ Wt, const float* __restrict__ bt,
                          float* __restrict__ temb, float half_dt, int total) {
    const int i = blockIdx.x * blockDim.x + threadIdx.x;
    if (i < total) {
        const int j = i >> 9, n = i & 511;
        temb[i] = (j * half_dt) * Wt[n] + bt[n];
    }
}

extern "C" void kernel_launch(void* const* d_in, const int* in_sizes, int n_in,
                              void* d_out, int out_size, void* d_ws, size_t ws_size,
                              hipStream_t stream) {
    const float* h_in = (const float*)d_in[0];
    const float* W1 = (const float*)d_in[1];
    const float* b1 = (const float*)d_in[2];
    const float* W2 = (const float*)d_in[3];
    const float* b2 = (const float*)d_in[4];
    const float* W3 = (const float*)d_in[5];
    const float* b3 = (const float*)d_in[6];
    const float* Wt = (const float*)d_in[7];
    const float* bt = (const float*)d_in[8];
    const int H = 512, H2 = 1024;
    const float dt = 0.1f;

    char* ws = (char*)d_ws;
    auto alloc = [&](size_t bytes) {
        char* p = ws;
        ws += (bytes + 255) & ~(size_t)255;
        return p;
    };
    bf16* W1b = (bf16*)alloc((size_t)H2 * H * 2);
    int8_t* W2i = (int8_t*)alloc((size_t)H2 * H2);      // i8, per-row scaled
    float* dqv  = (float*)alloc((size_t)H2 * 4);        // per-row dequant
    bf16* W3b = (bf16*)alloc((size_t)H * H2 * 2);
    float* temb = (float*)alloc((size_t)21 * H * 4);
    float* h_fin = (float*)d_out;   // final h (fp32), written once at s==9

    {
        int n = H2 * H;
        f2b_kern<<<(n + 255) / 256, 256, 0, stream>>>(W1, W1b, n);
        quantW2_row<<<H2, 256, 0, stream>>>(W2, H2, W2i, dqv);
        n = H * H2;
        f2b_kern<<<(n + 255) / 256, 256, 0, stream>>>(W3, W3b, n);
        const int total = 21 * H;
        temb_kern<<<(total + 255) / 256, 256, 0, stream>>>(Wt, bt, temb, dt * 0.5f, total);
    }

    // One plain launch: 256 blocks (1/CU) x 512 threads, zero grid syncs,
    // activations LDS-resident, weights L2-resident.
    ode_lds<<<dim3(256), dim3(512), 0, stream>>>(
        h_in, h_fin, W1b, b1, W2i, dqv, b2, W3b, b3, temb);
}